// Round 9
// baseline (4513.330 us; speedup 1.0000x reference)
//
#include <hip/hip_runtime.h>
#include <hip/hip_cooperative_groups.h>
#include <math.h>

namespace cg = cooperative_groups;

#define IB 1025
#define JF 4096
#define EPSF 1e-10f
#define NCH 256   // j-chunks for partial phases (16 j each)

// ---------------- helpers ----------------
__device__ __forceinline__ void load8(const float* __restrict__ base, int i, float v[8]) {
  const float4* b4 = (const float4*)(base + i * 8);
  float4 a = b4[0], b = b4[1];
  v[0]=a.x; v[1]=a.y; v[2]=a.z; v[3]=a.w; v[4]=b.x; v[5]=b.y; v[6]=b.z; v[7]=b.w;
}
__device__ __forceinline__ float dot8(const float a[8], const float b[8]) {
  float s = a[0]*b[0];
#pragma unroll
  for (int k=1;k<8;k++) s += a[k]*b[k];
  return s;
}
__device__ __forceinline__ float dot8s(const float a[8], const float* __restrict__ b) {
  float s = a[0]*b[0];
#pragma unroll
  for (int k=1;k<8;k++) s += a[k]*b[k];
  return s;
}

__device__ void dlaev2_dev(double a, double b, double c,
                           double& rt1, double& rt2, double& cs1, double& sn1) {
  double sm = a + c, df = a - c;
  double adf = fabs(df);
  double tb = b + b;
  double ab = fabs(tb);
  double acmx, acmn;
  if (fabs(a) > fabs(c)) { acmx = a; acmn = c; } else { acmx = c; acmn = a; }
  double rt;
  if (adf > ab)      { double t = ab/adf; rt = adf*sqrt(1.0 + t*t); }
  else if (adf < ab) { double t = adf/ab; rt = ab*sqrt(1.0 + t*t); }
  else               rt = ab*sqrt(2.0);
  int sgn1;
  if (sm < 0.0)      { rt1 = 0.5*(sm - rt); sgn1 = -1; rt2 = (acmx/rt1)*acmn - (b/rt1)*b; }
  else if (sm > 0.0) { rt1 = 0.5*(sm + rt); sgn1 =  1; rt2 = (acmx/rt1)*acmn - (b/rt1)*b; }
  else               { rt1 = 0.5*rt; rt2 = -0.5*rt; sgn1 = 1; }
  double cs; int sgn2;
  if (df >= 0.0) { cs = df + rt; sgn2 = 1; } else { cs = df - rt; sgn2 = -1; }
  double acs = fabs(cs);
  if (acs > ab) {
    double ct = -tb/cs;
    sn1 = 1.0/sqrt(1.0 + ct*ct);
    cs1 = ct*sn1;
  } else {
    if (ab == 0.0) { cs1 = 1.0; sn1 = 0.0; }
    else { double tn = -cs/tb; cs1 = 1.0/sqrt(1.0 + tn*tn); sn1 = tn*cs1; }
  }
  if (sgn1 == sgn2) { double tn = cs1; cs1 = -sn1; sn1 = tn; }
}

// ---- stage V chunk (16 j x 8 k x {s,n}) into LDS ----
#define STAGE_V16(j0) do {                                                  \
    int t_ = tx;                                                            \
    if (t_ < 128) { int jj_ = t_ >> 3, k_ = t_ & 7;                         \
      vsh[jj_][k_] = Vs[k_*JF + (j0) + jj_]; }                              \
    else { int u_ = t_ - 128; int jj_ = u_ >> 3, k_ = u_ & 7;               \
      vnh[jj_][k_] = Vn[k_*JF + (j0) + jj_]; }                              \
    __syncthreads();                                                        \
  } while (0)

// =======================================================================
__global__ __launch_bounds__(256, 4) void mega(
    const float2* __restrict__ X2,
    const float* __restrict__ Ts_in, const float* __restrict__ Vs_in,
    const float* __restrict__ Tn_in, const float* __restrict__ Vn_in,
    float* __restrict__ ws, float* __restrict__ out) {
  cg::grid_group grid = cg::this_grid();
  const int tx = threadIdx.x;
  const int nb = gridDim.x;

  float* Pt  = ws;                       // tail lam partials
  float* Ts  = ws + 1049600 + 16448;
  float* Vs  = Ts + 8200;
  float* Tn  = Vs + 32768;
  float* Vn  = Tn + 8200;
  float* lam = Vn + 32768;
  float* Wm  = lam + 1028;

  float2* m0 = (float2*)out;
  float2* m1 = m0 + (size_t)JF*IB;
  float* p1 = out + 2*(size_t)JF*IB;
  float* pn = p1 + (size_t)JF*IB;
  float* Pbig = out;                     // main-loop partials (m0 slice, dead until tail)

  __shared__ float vsh[16][8], vnh[16][8];
  __shared__ float redA[2][4][64];
  __shared__ float redB[4][16];
  __shared__ double gsh[8][64];

  // ---- init ----
  for (int wu = blockIdx.x; wu < 128; wu += nb) {
    int idx = wu * 256 + tx;
    if (idx < 8*JF) { Vs[idx] = Vs_in[idx]; Vn[idx] = Vn_in[idx]; }
    if (idx < IB*8) { Ts[idx] = Ts_in[idx]; Tn[idx] = Tn_in[idx]; }
    if (idx < IB) {
      lam[idx] = 1.0f;
      float* w = Wm + idx*8;
      w[0]=1.f; w[1]=0.f; w[2]=0.f; w[3]=0.f; w[4]=0.f; w[5]=0.f; w[6]=1.f; w[7]=0.f;
    }
  }
  grid.sync();

  for (int it = 0; it < 5; ++it) {
    // ---- P1: p1/pn + Ts partials ----
    for (int wu = blockIdx.x; wu < 5*NCH; wu += nb) {
      int ib = wu % 5, jc = wu / 5;
      int i = ib*256 + tx;
      int j0 = jc*16;
      STAGE_V16(j0);
      if (i < IB) {
        float ts[8], tn[8]; load8(Ts,i,ts); load8(Tn,i,tn);
        float lamv = lam[i];
        const float4* W4 = (const float4*)Wm;
        float4 wa = W4[i*2], wb = W4[i*2+1];
        float num[8] = {0,0,0,0,0,0,0,0}, den[8] = {0,0,0,0,0,0,0,0};
#pragma unroll 4
        for (int jj = 0; jj < 16; jj++) {
          int j = j0 + jj;
          float2 x0 = X2[j*IB + i];
          float2 x1 = X2[(JF + j)*IB + i];
          float y0r = wa.x*x0.x + wa.y*x0.y + wa.z*x1.x + wa.w*x1.y;
          float y0i = wa.x*x0.y - wa.y*x0.x + wa.z*x1.y - wa.w*x1.x;
          float y1r = wb.x*x0.x + wb.y*x0.y + wb.z*x1.x + wb.w*x1.y;
          float y1i = wb.x*x0.y - wb.y*x0.x + wb.z*x1.y - wb.w*x1.x;
          float pv  = y0r*y0r + y0i*y0i;
          float pnv = y1r*y1r + y1i*y1i;
          p1[j*IB + i] = pv;
          pn[j*IB + i] = pnv;
          float rs = fmaxf(dot8s(ts, vsh[jj]), EPSF);
          float rn = fmaxf(dot8s(tn, vnh[jj]), EPSF);
          float iL = 1.f / fmaxf(rs + rn*lamv, EPSF);
          float a2 = pv*iL*iL;
#pragma unroll
          for (int k=0;k<8;k++){ num[k] += a2*vsh[jj][k]; den[k] += iL*vsh[jj][k]; }
        }
#pragma unroll
        for (int k=0;k<8;k++){
          Pbig[(jc*16+k)*IB + i] = num[k];
          Pbig[(jc*16+8+k)*IB + i] = den[k];
        }
      }
      __syncthreads();
    }
    grid.sync();

    // ---- P2: Ts finalize ----
    for (int wu = blockIdx.x; wu < 17*8; wu += nb) {
      int ibb = wu % 17, k = wu / 17;
      int ii = tx & 63, g = tx >> 6;
      int i = ibb*64 + ii;
      float num = 0.f, den = 0.f;
      if (i < IB) {
        for (int t = 0; t < 64; t++) {
          int c = g*64 + t;
          num += Pbig[(c*16+k)*IB + i];
          den += Pbig[(c*16+8+k)*IB + i];
        }
      }
      redA[0][g][ii] = num; redA[1][g][ii] = den;
      __syncthreads();
      if (g == 0 && i < IB) {
        float n_ = redA[0][0][ii]+redA[0][1][ii]+redA[0][2][ii]+redA[0][3][ii];
        float d_ = redA[1][0][ii]+redA[1][1][ii]+redA[1][2][ii]+redA[1][3][ii];
        float t = Ts[i*8+k];
        Ts[i*8+k] = fmaxf(t * sqrtf(n_/(d_+EPSF)), EPSF);
      }
      __syncthreads();
    }
    grid.sync();

    // ---- P3: Vs update ----
    for (int wu = blockIdx.x; wu < JF; wu += nb) {
      int j = wu;
      float vs[8], vn[8];
#pragma unroll
      for (int k=0;k<8;k++){ vs[k]=Vs[k*JF+j]; vn[k]=Vn[k*JF+j]; }
      float acc[16];
#pragma unroll
      for (int v=0;v<16;v++) acc[v] = 0.f;
      for (int s = 0; s < 5; s++) {
        int i = s*256 + tx;
        if (i < IB) {
          float ts[8], tn[8];
          load8(Ts, i, ts); load8(Tn, i, tn);
          float lamv = lam[i];
          float pv = p1[j*IB + i];
          float rs = fmaxf(dot8(ts, vs), EPSF);
          float rn = fmaxf(dot8(tn, vn), EPSF);
          float iL = 1.f / fmaxf(rs + rn*lamv, EPSF);
          float a2 = pv*iL*iL;
#pragma unroll
          for (int k=0;k<8;k++){ acc[k] += ts[k]*a2; acc[8+k] += ts[k]*iL; }
        }
      }
      int wid = tx >> 6, lane = tx & 63;
#pragma unroll
      for (int v=0;v<16;v++){
        float x = acc[v];
        x += __shfl_down(x, 32, 64); x += __shfl_down(x, 16, 64);
        x += __shfl_down(x, 8, 64);  x += __shfl_down(x, 4, 64);
        x += __shfl_down(x, 2, 64);  x += __shfl_down(x, 1, 64);
        if (lane == 0) redB[wid][v] = x;
      }
      __syncthreads();
      if (tx == 0) {
#pragma unroll
        for (int k=0;k<8;k++){
          float n_ = redB[0][k]+redB[1][k]+redB[2][k]+redB[3][k];
          float d_ = redB[0][8+k]+redB[1][8+k]+redB[2][8+k]+redB[3][8+k];
          Vs[k*JF+j] = fmaxf(vs[k] * sqrtf(n_/(d_+EPSF)), EPSF);
        }
      }
      __syncthreads();
    }
    grid.sync();

    // ---- P4: Tn partials ----
    for (int wu = blockIdx.x; wu < 5*NCH; wu += nb) {
      int ib = wu % 5, jc = wu / 5;
      int i = ib*256 + tx;
      int j0 = jc*16;
      STAGE_V16(j0);
      if (i < IB) {
        float ts[8], tn[8]; load8(Ts,i,ts); load8(Tn,i,tn);
        float lamv = lam[i];
        float num[8] = {0,0,0,0,0,0,0,0}, den[8] = {0,0,0,0,0,0,0,0};
#pragma unroll 4
        for (int jj = 0; jj < 16; jj++) {
          int j = j0 + jj;
          float pv = p1[j*IB + i];
          float pnv = pn[j*IB + i];
          float rs = fmaxf(dot8s(ts, vsh[jj]), EPSF);
          float rn = fmaxf(dot8s(tn, vnh[jj]), EPSF);
          float iL = 1.f / fmaxf(rs + rn*lamv, EPSF);
          float irn = 1.f / rn;
          float a2 = lamv*pv*iL*iL + pnv*irn*irn;
          float b2 = lamv*iL + irn;
#pragma unroll
          for (int k=0;k<8;k++){ num[k] += a2*vnh[jj][k]; den[k] += b2*vnh[jj][k]; }
        }
#pragma unroll
        for (int k=0;k<8;k++){
          Pbig[(jc*16+k)*IB + i] = num[k];
          Pbig[(jc*16+8+k)*IB + i] = den[k];
        }
      }
      __syncthreads();
    }
    grid.sync();

    // ---- P5: Tn finalize ----
    for (int wu = blockIdx.x; wu < 17*8; wu += nb) {
      int ibb = wu % 17, k = wu / 17;
      int ii = tx & 63, g = tx >> 6;
      int i = ibb*64 + ii;
      float num = 0.f, den = 0.f;
      if (i < IB) {
        for (int t = 0; t < 64; t++) {
          int c = g*64 + t;
          num += Pbig[(c*16+k)*IB + i];
          den += Pbig[(c*16+8+k)*IB + i];
        }
      }
      redA[0][g][ii] = num; redA[1][g][ii] = den;
      __syncthreads();
      if (g == 0 && i < IB) {
        float n_ = redA[0][0][ii]+redA[0][1][ii]+redA[0][2][ii]+redA[0][3][ii];
        float d_ = redA[1][0][ii]+redA[1][1][ii]+redA[1][2][ii]+redA[1][3][ii];
        float t = Tn[i*8+k];
        Tn[i*8+k] = fmaxf(t * sqrtf(n_/(d_+EPSF)), EPSF);
      }
      __syncthreads();
    }
    grid.sync();

    // ---- P6: Vn update ----
    for (int wu = blockIdx.x; wu < JF; wu += nb) {
      int j = wu;
      float vs[8], vn[8];
#pragma unroll
      for (int k=0;k<8;k++){ vs[k]=Vs[k*JF+j]; vn[k]=Vn[k*JF+j]; }
      float acc[16];
#pragma unroll
      for (int v=0;v<16;v++) acc[v] = 0.f;
      for (int s = 0; s < 5; s++) {
        int i = s*256 + tx;
        if (i < IB) {
          float ts[8], tn[8];
          load8(Ts, i, ts); load8(Tn, i, tn);
          float lamv = lam[i];
          float pv = p1[j*IB + i];
          float pnv = pn[j*IB + i];
          float rs = fmaxf(dot8(ts, vs), EPSF);
          float rn = fmaxf(dot8(tn, vn), EPSF);
          float iL = 1.f / fmaxf(rs + rn*lamv, EPSF);
          float irn = 1.f / rn;
          float a2 = lamv*pv*iL*iL + pnv*irn*irn;
          float b2 = lamv*iL + irn;
#pragma unroll
          for (int k=0;k<8;k++){ acc[k] += tn[k]*a2; acc[8+k] += tn[k]*b2; }
        }
      }
      int wid = tx >> 6, lane = tx & 63;
#pragma unroll
      for (int v=0;v<16;v++){
        float x = acc[v];
        x += __shfl_down(x, 32, 64); x += __shfl_down(x, 16, 64);
        x += __shfl_down(x, 8, 64);  x += __shfl_down(x, 4, 64);
        x += __shfl_down(x, 2, 64);  x += __shfl_down(x, 1, 64);
        if (lane == 0) redB[wid][v] = x;
      }
      __syncthreads();
      if (tx == 0) {
#pragma unroll
        for (int k=0;k<8;k++){
          float n_ = redB[0][k]+redB[1][k]+redB[2][k]+redB[3][k];
          float d_ = redB[0][8+k]+redB[1][8+k]+redB[2][8+k]+redB[3][8+k];
          Vn[k*JF+j] = fmaxf(vn[k] * sqrtf(n_/(d_+EPSF)), EPSF);
        }
      }
      __syncthreads();
    }
    grid.sync();

    // ---- P7: lam partials ----
    for (int wu = blockIdx.x; wu < 5*NCH; wu += nb) {
      int ib = wu % 5, jc = wu / 5;
      int i = ib*256 + tx;
      int j0 = jc*16;
      STAGE_V16(j0);
      if (i < IB) {
        float ts[8], tn[8]; load8(Ts,i,ts); load8(Tn,i,tn);
        float lamv = lam[i];
        float lnum = 0.f, lden = 0.f;
#pragma unroll 4
        for (int jj = 0; jj < 16; jj++) {
          int j = j0 + jj;
          float pv = p1[j*IB + i];
          float rs = fmaxf(dot8s(ts, vsh[jj]), EPSF);
          float rn = fmaxf(dot8s(tn, vnh[jj]), EPSF);
          float iL = 1.f / fmaxf(rs + rn*lamv, EPSF);
          lnum += rn*pv*iL*iL;
          lden += rn*iL;
        }
        Pbig[(jc*2+0)*IB + i] = lnum;
        Pbig[(jc*2+1)*IB + i] = lden;
      }
      __syncthreads();
    }
    grid.sync();

    // ---- P8: lam finalize ----
    for (int wu = blockIdx.x; wu < 17; wu += nb) {
      int ii = tx & 63, g = tx >> 6;
      int i = wu*64 + ii;
      float num = 0.f, den = 0.f;
      if (i < IB) {
        for (int t = 0; t < 64; t++) {
          int c = g*64 + t;
          num += Pbig[(c*2+0)*IB + i];
          den += Pbig[(c*2+1)*IB + i];
        }
      }
      redA[0][g][ii] = num; redA[1][g][ii] = den;
      __syncthreads();
      if (g == 0 && i < IB) {
        float n_ = redA[0][0][ii]+redA[0][1][ii]+redA[0][2][ii]+redA[0][3][ii];
        float d_ = redA[1][0][ii]+redA[1][1][ii]+redA[1][2][ii]+redA[1][3][ii];
        lam[i] = fmaxf(lam[i] * sqrtf(n_/(d_+EPSF)), EPSF);
      }
      __syncthreads();
    }
    grid.sync();

    // ---- P9: G partials ----
    for (int wu = blockIdx.x; wu < 5*NCH; wu += nb) {
      int ib = wu % 5, jc = wu / 5;
      int i = ib*256 + tx;
      int j0 = jc*16;
      STAGE_V16(j0);
      if (i < IB) {
        float ts[8], tn[8]; load8(Ts,i,ts); load8(Tn,i,tn);
        float lamv = lam[i];
        float g8[8];
#pragma unroll
        for (int v=0;v<8;v++) g8[v] = 0.f;
#pragma unroll 4
        for (int jj = 0; jj < 16; jj++) {
          int j = j0 + jj;
          float2 x0 = X2[j*IB + i];
          float2 x1 = X2[(JF + j)*IB + i];
          float rs = fmaxf(dot8s(ts, vsh[jj]), EPSF);
          float rn = fmaxf(dot8s(tn, vnh[jj]), EPSF);
          float wsc = 1.f / fmaxf(rs + rn*lamv, EPSF);
          float wn = 1.f / rn;
          float m00 = x0.x*x0.x + x0.y*x0.y;
          float m11 = x1.x*x1.x + x1.y*x1.y;
          float m01r = x0.x*x1.x + x0.y*x1.y;
          float m01i = x0.y*x1.x - x0.x*x1.y;
          g8[0] += m00*wsc; g8[1] += m11*wsc; g8[2] += m01r*wsc; g8[3] += m01i*wsc;
          g8[4] += m00*wn;  g8[5] += m11*wn;  g8[6] += m01r*wn;  g8[7] += m01i*wn;
        }
#pragma unroll
        for (int v=0;v<8;v++) Pbig[(jc*8+v)*IB + i] = g8[v];
      }
      __syncthreads();
    }
    grid.sync();

    // ---- P10: G finalize + eig ----
    for (int wu = blockIdx.x; wu < 17; wu += nb) {
      int ii = tx & 63, g = tx >> 6;   // g in 0..3, handles v=g and v=4+g
      int i = wu*64 + ii;
      double s0 = 0.0, s1 = 0.0;
      if (i < IB) {
        for (int c = 0; c < NCH; c++) {
          s0 += (double)Pbig[(c*8+g)*IB + i];
          s1 += (double)Pbig[(c*8+4+g)*IB + i];
        }
      }
      gsh[g][ii] = s0; gsh[4+g][ii] = s1;
      __syncthreads();
      if (g == 0 && i < IB) {
        const double EPSD = 1e-10;
        double as  = gsh[0][ii]/4096.0 + EPSD;
        double cs_ = gsh[1][ii]/4096.0 + EPSD;
        double bsr = gsh[2][ii]/4096.0, bsi = gsh[3][ii]/4096.0;
        double dn  = gsh[4][ii]/4096.0 + EPSD;
        double fn  = gsh[5][ii]/4096.0 + EPSD;
        double enr = gsh[6][ii]/4096.0, eni = gsh[7][ii]/4096.0;
        double l11 = sqrt(as);
        double il11 = 1.0/l11;
        double l21r = bsr*il11, l21i = -bsi*il11;
        double l22sq = cs_ - (l21r*l21r + l21i*l21i);
        double l22 = sqrt(fmax(l22sq, 0.0));
        double p = il11, r = 1.0/l22;
        double qr = -l21r*p*r, qi = -l21i*p*r;
        double C00  = p*p*dn;
        double C01r = p*(dn*qr + enr*r);
        double C01i = p*(-dn*qi + eni*r);
        double C11  = (qr*qr+qi*qi)*dn + 2.0*r*(qr*enr - qi*eni) + r*r*fn;
        double br = C01r, bi = C01i;
        double e_, hqr, hqi;
        if (bi == 0.0) { e_ = br; hqr = 1.0; hqi = 0.0; }
        else {
          double ab_ = sqrt(br*br + bi*bi);
          e_ = (br >= 0.0) ? -ab_ : ab_;
          hqr = br / e_; hqi = -bi / e_;
        }
        double ut0, ub0, ut1, ub1;
        const double MEPS = 1.1102230246251565e-16;
        if (fabs(e_) <= sqrt(fabs(C00))*sqrt(fabs(C11))*MEPS) {
          if (C11 < C00) { ut0=0.0; ub0=1.0; ut1=1.0; ub1=0.0; }
          else           { ut0=1.0; ub0=0.0; ut1=0.0; ub1=1.0; }
        } else {
          double rt1, rt2, cs1, sn1;
          dlaev2_dev(C00, e_, C11, rt1, rt2, cs1, sn1);
          if (rt2 < rt1) { ut0=-sn1; ub0=cs1; ut1=cs1;  ub1=sn1; }
          else           { ut0=cs1;  ub0=sn1; ut1=-sn1; ub1=cs1; }
        }
        double chr = qr*hqr + qi*hqi;
        double chi = qr*hqi - qi*hqr;
        double v0tr = p*ut0 + chr*ub0, v0ti = chi*ub0;
        double v0br = r*hqr*ub0,       v0bi = r*hqi*ub0;
        double v1tr = p*ut1 + chr*ub1, v1ti = chi*ub1;
        double v1br = r*hqr*ub1,       v1bi = r*hqi*ub1;
        double q0 = as*(v0tr*v0tr+v0ti*v0ti) + cs_*(v0br*v0br+v0bi*v0bi)
                  + 2.0*((bsr*v0br - bsi*v0bi)*v0tr + (bsr*v0bi + bsi*v0br)*v0ti);
        double q1 = dn*(v1tr*v1tr+v1ti*v1ti) + fn*(v1br*v1br+v1bi*v1bi)
                  + 2.0*((enr*v1br - eni*v1bi)*v1tr + (enr*v1bi + eni*v1br)*v1ti);
        double sc0 = 1.0/sqrt(fmax(q0, 1e-10));
        double sc1 = 1.0/sqrt(fmax(q1, 1e-10));
        float* w = Wm + i*8;
        w[0] = (float)(v0tr*sc0); w[1] = (float)(v0ti*sc0);
        w[2] = (float)(v0br*sc0); w[3] = (float)(v0bi*sc0);
        w[4] = (float)(v1tr*sc1); w[5] = (float)(v1ti*sc1);
        w[6] = (float)(v1br*sc1); w[7] = (float)(v1bi*sc1);
      }
      __syncthreads();
    }
    grid.sync();
  }

  // ---- tail: p1/pn + (r_s,r_n) into m0 (elementwise) ----
  for (int wu = blockIdx.x; wu < 5*JF; wu += nb) {
    int ib = wu % 5, j = wu / 5;
    int i = ib*256 + tx;
    if (i < IB) {
      float2 x0 = X2[j*IB + i];
      float2 x1 = X2[(JF + j)*IB + i];
      const float4* W4 = (const float4*)Wm;
      float4 wa = W4[i*2], wb = W4[i*2+1];
      float y0r = wa.x*x0.x + wa.y*x0.y + wa.z*x1.x + wa.w*x1.y;
      float y0i = wa.x*x0.y - wa.y*x0.x + wa.z*x1.y - wa.w*x1.x;
      float y1r = wb.x*x0.x + wb.y*x0.y + wb.z*x1.x + wb.w*x1.y;
      float y1i = wb.x*x0.y - wb.y*x0.x + wb.z*x1.y - wb.w*x1.x;
      p1[j*IB + i] = y0r*y0r + y0i*y0i;
      pn[j*IB + i] = y1r*y1r + y1i*y1i;
      float ts[8], tn[8];
      load8(Ts, i, ts); load8(Tn, i, tn);
      float rs = 0.f, rn = 0.f;
#pragma unroll
      for (int k=0;k<8;k++){ rs += ts[k]*Vs[k*JF+j]; rn += tn[k]*Vn[k*JF+j]; }
      m0[j*IB + i] = make_float2(fmaxf(rs, EPSF), fmaxf(rn, EPSF));
    }
  }
  grid.sync();

  // ---- 3 simplified iterations ----
  for (int itr = 0; itr < 3; itr++) {
    for (int wu = blockIdx.x; wu < 5*NCH; wu += nb) {
      int ib = wu % 5, jc = wu / 5;
      int i = ib*256 + tx;
      if (i < IB) {
        float lamv = lam[i];
        float lnum = 0.f, lden = 0.f;
        int j0 = jc * 16;
#pragma unroll 4
        for (int jj = 0; jj < 16; jj++) {
          int j = j0 + jj;
          float2 rr = m0[j*IB + i];
          float rs = rr.x, rn = rr.y;
          float pv = p1[j*IB + i], pnv = pn[j*IB + i];
          float iL = 1.f / fmaxf(rs + rn*lamv, EPSF);
          float irs = 1.f / (rs + EPSF);
          float rs2 = fmaxf(rs * sqrtf((pv*iL*iL) / (iL + 1.1f*irs + EPSF)), EPSF);
          float iL2 = 1.f / fmaxf(rs2 + rn*lamv, EPSF);
          float irn = 1.f / (rn + EPSF);
          float rn2 = fmaxf(rn * sqrtf((lamv*pv*iL2*iL2 + pnv*irn*irn) / (lamv*iL2 + irn + EPSF)), EPSF);
          float iL3 = 1.f / fmaxf(rs2 + rn2*lamv, EPSF);
          m0[j*IB + i] = make_float2(rs2, rn2);
          lnum += rn2*pv*iL3*iL3;
          lden += rn2*iL3;
        }
        Pt[(jc*2+0)*IB + i] = lnum;
        Pt[(jc*2+1)*IB + i] = lden;
      }
    }
    grid.sync();
    for (int wu = blockIdx.x; wu < 17; wu += nb) {
      int ii = tx & 63, g = tx >> 6;
      int i = wu*64 + ii;
      float num = 0.f, den = 0.f;
      if (i < IB) {
        for (int t = 0; t < 64; t++) {
          int c = g*64 + t;
          num += Pt[(c*2+0)*IB + i];
          den += Pt[(c*2+1)*IB + i];
        }
      }
      redA[0][g][ii] = num; redA[1][g][ii] = den;
      __syncthreads();
      if (g == 0 && i < IB) {
        float n_ = redA[0][0][ii]+redA[0][1][ii]+redA[0][2][ii]+redA[0][3][ii];
        float d_ = redA[1][0][ii]+redA[1][1][ii]+redA[1][2][ii]+redA[1][3][ii];
        lam[i] = fmaxf(lam[i] * sqrtf(n_/(d_+EPSF)), EPSF);
      }
      __syncthreads();
    }
    grid.sync();
  }

  // ---- final: S = r_s/Lam * Y0 ----
  for (int wu = blockIdx.x; wu < 5*JF; wu += nb) {
    int ib = wu % 5, j = wu / 5;
    int i = ib*256 + tx;
    if (i < IB) {
      float2 rr = m0[j*IB + i];
      float L = fmaxf(rr.x + rr.y*lam[i], EPSF);
      float gsc = rr.x / L;
      float2 x0 = X2[j*IB + i];
      float2 x1 = X2[(JF + j)*IB + i];
      float4 wa = ((const float4*)Wm)[i*2];
      float y0r = wa.x*x0.x + wa.y*x0.y + wa.z*x1.x + wa.w*x1.y;
      float y0i = wa.x*x0.y - wa.y*x0.x + wa.z*x1.y - wa.w*x1.x;
      float2 s = make_float2(gsc*y0r, gsc*y0i);
      m0[j*IB + i] = s;
      m1[j*IB + i] = s;
    }
  }
}

// ---------------- launch ----------------
extern "C" void kernel_launch(void* const* d_in, const int* in_sizes, int n_in,
                              void* d_out, int out_size, void* d_ws, size_t ws_size,
                              hipStream_t stream) {
  (void)in_sizes; (void)n_in; (void)out_size; (void)ws_size;
  const float2* X2 = (const float2*)d_in[0];
  const float* Ts_in = (const float*)d_in[1];
  const float* Vs_in = (const float*)d_in[2];
  const float* Tn_in = (const float*)d_in[3];
  const float* Vn_in = (const float*)d_in[4];
  float* ws = (float*)d_ws;
  float* out = (float*)d_out;

  int nblk = 0;
  if (hipOccupancyMaxActiveBlocksPerMultiprocessor(&nblk,
        reinterpret_cast<const void*>(mega), 256, 0) != hipSuccess || nblk < 1)
    nblk = 2;   // conservative co-residency fallback
  if (nblk > 8) nblk = 8;
  int gridBlocks = nblk * 256;   // MI355X: 256 CUs

  void* args[] = { (void*)&X2, (void*)&Ts_in, (void*)&Vs_in,
                   (void*)&Tn_in, (void*)&Vn_in, (void*)&ws, (void*)&out };
  hipLaunchCooperativeKernel(reinterpret_cast<const void*>(mega),
                             dim3(gridBlocks), dim3(256), args, 0, stream);
}

// Round 10
// 913.043 us; speedup vs baseline: 4.9432x; 4.9432x over previous
//
#include <hip/hip_runtime.h>
#include <math.h>

#define IB 1025
#define JF 4096
#define EPSF 1e-10f
#define NCH 256   // j-chunks for partial kernels (16 j each)

// ---------------- helpers ----------------
__device__ __forceinline__ void load8(const float* __restrict__ base, int i, float v[8]) {
  const float4* b4 = (const float4*)(base + i * 8);
  float4 a = b4[0], b = b4[1];
  v[0]=a.x; v[1]=a.y; v[2]=a.z; v[3]=a.w; v[4]=b.x; v[5]=b.y; v[6]=b.z; v[7]=b.w;
}
__device__ __forceinline__ float dot8(const float a[8], const float b[8]) {
  float s = a[0]*b[0];
#pragma unroll
  for (int k=1;k<8;k++) s += a[k]*b[k];
  return s;
}
__device__ __forceinline__ float dot8s(const float a[8], const float* __restrict__ b) {
  float s = a[0]*b[0];
#pragma unroll
  for (int k=1;k<8;k++) s += a[k]*b[k];
  return s;
}

// ---- stage V chunk (16 j x 8 k x {s,n}) into LDS: one load per thread ----
#define STAGE_V16(vsh, vnh, Vs, Vn, j0) do {                                \
    int t_ = threadIdx.x;                                                   \
    if (t_ < 128) { int jj_ = t_ >> 3, k_ = t_ & 7;                         \
      vsh[jj_][k_] = Vs[k_*JF + (j0) + jj_]; }                              \
    else { int u_ = t_ - 128; int jj_ = u_ >> 3, k_ = u_ & 7;               \
      vnh[jj_][k_] = Vn[k_*JF + (j0) + jj_]; }                              \
    __syncthreads();                                                        \
  } while (0)

// ---------------- init ----------------
__global__ __launch_bounds__(256) void k_init(
    const float* __restrict__ Ts_in, const float* __restrict__ Vs_in,
    const float* __restrict__ Tn_in, const float* __restrict__ Vn_in,
    float* __restrict__ Ts, float* __restrict__ Vs,
    float* __restrict__ Tn, float* __restrict__ Vn,
    float* __restrict__ lam, float* __restrict__ Wm) {
  int idx = blockIdx.x * 256 + threadIdx.x;
  if (idx < 8 * JF) { Vs[idx] = Vs_in[idx]; Vn[idx] = Vn_in[idx]; }
  if (idx < IB * 8) { Ts[idx] = Ts_in[idx]; Tn[idx] = Tn_in[idx]; }
  if (idx < IB) {
    lam[idx] = 1.0f;
    float* w = Wm + idx * 8;
    w[0]=1.f; w[1]=0.f; w[2]=0.f; w[3]=0.f; w[4]=0.f; w[5]=0.f; w[6]=1.f; w[7]=0.f;
  }
}

// ---------------- fused p1/pn + T_s partials; 256 thr, 16 j per block ----------------
__global__ __launch_bounds__(256) void k_p1pn_ts(const float2* __restrict__ X2,
    const float* __restrict__ Wm,
    const float* __restrict__ Ts, const float* __restrict__ Vs,
    const float* __restrict__ Tn, const float* __restrict__ Vn,
    const float* __restrict__ lam,
    float* __restrict__ p1, float* __restrict__ pn, float* __restrict__ P) {
  __shared__ float vsh[16][8], vnh[16][8];
  int tx = threadIdx.x;
  int i = blockIdx.x * 256 + tx;
  int jc = blockIdx.y;
  int j0 = jc * 16;
  STAGE_V16(vsh, vnh, Vs, Vn, j0);
  if (i >= IB) return;
  float ts[8], tn[8];
  load8(Ts, i, ts); load8(Tn, i, tn);
  float lamv = lam[i];
  const float4* W4 = (const float4*)Wm;
  float4 wa = W4[i*2], wb = W4[i*2+1];
  float num[8] = {0,0,0,0,0,0,0,0}, den[8] = {0,0,0,0,0,0,0,0};
#pragma unroll 4
  for (int jj = 0; jj < 16; jj++) {
    int j = j0 + jj;
    float2 x0 = X2[j*IB + i];
    float2 x1 = X2[(JF + j)*IB + i];
    float y0r = wa.x*x0.x + wa.y*x0.y + wa.z*x1.x + wa.w*x1.y;
    float y0i = wa.x*x0.y - wa.y*x0.x + wa.z*x1.y - wa.w*x1.x;
    float y1r = wb.x*x0.x + wb.y*x0.y + wb.z*x1.x + wb.w*x1.y;
    float y1i = wb.x*x0.y - wb.y*x0.x + wb.z*x1.y - wb.w*x1.x;
    float pv  = y0r*y0r + y0i*y0i;
    float pnv = y1r*y1r + y1i*y1i;
    p1[j*IB + i] = pv;
    pn[j*IB + i] = pnv;
    float rs = fmaxf(dot8s(ts, vsh[jj]), EPSF);
    float rn = fmaxf(dot8s(tn, vnh[jj]), EPSF);
    float iL = 1.f / fmaxf(rs + rn*lamv, EPSF);
    float a2 = pv*iL*iL;
#pragma unroll
    for (int k=0;k<8;k++){ num[k] += a2*vsh[jj][k]; den[k] += iL*vsh[jj][k]; }
  }
#pragma unroll
  for (int k=0;k<8;k++){
    P[(jc*16+k)*IB + i] = num[k];
    P[(jc*16+8+k)*IB + i] = den[k];
  }
}

// ---------------- T finalize: 512 thr = 64 i x 8 groups, NCH chunks ----------------
__global__ __launch_bounds__(512) void k_t_final(const float* __restrict__ P, float* __restrict__ T) {
  int tx = threadIdx.x;
  int ii = tx & 63, g = tx >> 6;
  int i = blockIdx.x * 64 + ii;
  int k = blockIdx.y;
  float num = 0.f, den = 0.f;
  if (i < IB) {
    for (int t = 0; t < NCH/8; t++) {
      int c = g*(NCH/8) + t;
      num += P[(c*16+k)*IB + i];
      den += P[(c*16+8+k)*IB + i];
    }
  }
  __shared__ float red[2][8][64];
  red[0][g][ii] = num; red[1][g][ii] = den;
  __syncthreads();
  if (g == 0 && i < IB) {
    float n_ = 0.f, d_ = 0.f;
#pragma unroll
    for (int q=0;q<8;q++){ n_ += red[0][q][ii]; d_ += red[1][q][ii]; }
    float t = T[i*8+k];
    T[i*8+k] = fmaxf(t * sqrtf(n_/(d_+EPSF)), EPSF);
  }
}

// ---------------- V_s update ----------------
__global__ __launch_bounds__(256) void k_vs(const float* __restrict__ p1,
    const float* __restrict__ Ts, float* __restrict__ Vs,
    const float* __restrict__ Tn, const float* __restrict__ Vn,
    const float* __restrict__ lam) {
  int j = blockIdx.x;
  int tx = threadIdx.x;
  float vs[8], vn[8];
#pragma unroll
  for (int k=0;k<8;k++){ vs[k]=Vs[k*JF+j]; vn[k]=Vn[k*JF+j]; }
  float acc[16];
#pragma unroll
  for (int v=0;v<16;v++) acc[v] = 0.f;
  for (int s = 0; s < 5; s++) {
    int i = s*256 + tx;
    if (i < IB) {
      float ts[8], tn[8];
      load8(Ts, i, ts); load8(Tn, i, tn);
      float lamv = lam[i];
      float pv = p1[j*IB + i];
      float rs = fmaxf(dot8(ts, vs), EPSF);
      float rn = fmaxf(dot8(tn, vn), EPSF);
      float iL = 1.f / fmaxf(rs + rn*lamv, EPSF);
      float a2 = pv*iL*iL;
#pragma unroll
      for (int k=0;k<8;k++){ acc[k] += ts[k]*a2; acc[8+k] += ts[k]*iL; }
    }
  }
  __shared__ float red[4][16];
  int wid = tx >> 6, lane = tx & 63;
#pragma unroll
  for (int v=0;v<16;v++){
    float x = acc[v];
    x += __shfl_down(x, 32, 64); x += __shfl_down(x, 16, 64);
    x += __shfl_down(x, 8, 64);  x += __shfl_down(x, 4, 64);
    x += __shfl_down(x, 2, 64);  x += __shfl_down(x, 1, 64);
    if (lane == 0) red[wid][v] = x;
  }
  __syncthreads();
  if (tx == 0) {
#pragma unroll
    for (int k=0;k<8;k++){
      float n_ = red[0][k]+red[1][k]+red[2][k]+red[3][k];
      float d_ = red[0][8+k]+red[1][8+k]+red[2][8+k]+red[3][8+k];
      Vs[k*JF+j] = fmaxf(vs[k] * sqrtf(n_/(d_+EPSF)), EPSF);
    }
  }
}

// ---------------- T_n partials; 256 thr, 16 j per block ----------------
__global__ __launch_bounds__(256) void k_tn_partial(const float* __restrict__ p1,
    const float* __restrict__ pn,
    const float* __restrict__ Ts, const float* __restrict__ Vs,
    const float* __restrict__ Tn, const float* __restrict__ Vn,
    const float* __restrict__ lam, float* __restrict__ P) {
  __shared__ float vsh[16][8], vnh[16][8];
  int tx = threadIdx.x;
  int i = blockIdx.x * 256 + tx;
  int jc = blockIdx.y;
  int j0 = jc * 16;
  STAGE_V16(vsh, vnh, Vs, Vn, j0);
  if (i >= IB) return;
  float ts[8], tn[8];
  load8(Ts, i, ts); load8(Tn, i, tn);
  float lamv = lam[i];
  float num[8] = {0,0,0,0,0,0,0,0}, den[8] = {0,0,0,0,0,0,0,0};
#pragma unroll 4
  for (int jj = 0; jj < 16; jj++) {
    int j = j0 + jj;
    float pv = p1[j*IB + i];
    float pnv = pn[j*IB + i];
    float rs = fmaxf(dot8s(ts, vsh[jj]), EPSF);
    float rn = fmaxf(dot8s(tn, vnh[jj]), EPSF);
    float iL = 1.f / fmaxf(rs + rn*lamv, EPSF);
    float irn = 1.f / rn;
    float a2 = lamv*pv*iL*iL + pnv*irn*irn;
    float b2 = lamv*iL + irn;
#pragma unroll
    for (int k=0;k<8;k++){ num[k] += a2*vnh[jj][k]; den[k] += b2*vnh[jj][k]; }
  }
#pragma unroll
  for (int k=0;k<8;k++){
    P[(jc*16+k)*IB + i] = num[k];
    P[(jc*16+8+k)*IB + i] = den[k];
  }
}

// ---------------- V_n update ----------------
__global__ __launch_bounds__(256) void k_vn(const float* __restrict__ p1,
    const float* __restrict__ pn,
    const float* __restrict__ Ts, const float* __restrict__ Vs,
    const float* __restrict__ Tn, float* __restrict__ Vn,
    const float* __restrict__ lam) {
  int j = blockIdx.x;
  int tx = threadIdx.x;
  float vs[8], vn[8];
#pragma unroll
  for (int k=0;k<8;k++){ vs[k]=Vs[k*JF+j]; vn[k]=Vn[k*JF+j]; }
  float acc[16];
#pragma unroll
  for (int v=0;v<16;v++) acc[v] = 0.f;
  for (int s = 0; s < 5; s++) {
    int i = s*256 + tx;
    if (i < IB) {
      float ts[8], tn[8];
      load8(Ts, i, ts); load8(Tn, i, tn);
      float lamv = lam[i];
      float pv = p1[j*IB + i];
      float pnv = pn[j*IB + i];
      float rs = fmaxf(dot8(ts, vs), EPSF);
      float rn = fmaxf(dot8(tn, vn), EPSF);
      float iL = 1.f / fmaxf(rs + rn*lamv, EPSF);
      float irn = 1.f / rn;
      float a2 = lamv*pv*iL*iL + pnv*irn*irn;
      float b2 = lamv*iL + irn;
#pragma unroll
      for (int k=0;k<8;k++){ acc[k] += tn[k]*a2; acc[8+k] += tn[k]*b2; }
    }
  }
  __shared__ float red[4][16];
  int wid = tx >> 6, lane = tx & 63;
#pragma unroll
  for (int v=0;v<16;v++){
    float x = acc[v];
    x += __shfl_down(x, 32, 64); x += __shfl_down(x, 16, 64);
    x += __shfl_down(x, 8, 64);  x += __shfl_down(x, 4, 64);
    x += __shfl_down(x, 2, 64);  x += __shfl_down(x, 1, 64);
    if (lane == 0) red[wid][v] = x;
  }
  __syncthreads();
  if (tx == 0) {
#pragma unroll
    for (int k=0;k<8;k++){
      float n_ = red[0][k]+red[1][k]+red[2][k]+red[3][k];
      float d_ = red[0][8+k]+red[1][8+k]+red[2][8+k]+red[3][8+k];
      Vn[k*JF+j] = fmaxf(vn[k] * sqrtf(n_/(d_+EPSF)), EPSF);
    }
  }
}

// ---------------- lam partials; 256 thr, 16 j per block ----------------
__global__ __launch_bounds__(256) void k_lam_partial(const float* __restrict__ p1,
    const float* __restrict__ Ts, const float* __restrict__ Vs,
    const float* __restrict__ Tn, const float* __restrict__ Vn,
    const float* __restrict__ lam, float* __restrict__ P) {
  __shared__ float vsh[16][8], vnh[16][8];
  int tx = threadIdx.x;
  int i = blockIdx.x * 256 + tx;
  int jc = blockIdx.y;
  int j0 = jc * 16;
  STAGE_V16(vsh, vnh, Vs, Vn, j0);
  if (i >= IB) return;
  float ts[8], tn[8];
  load8(Ts, i, ts); load8(Tn, i, tn);
  float lamv = lam[i];
  float lnum = 0.f, lden = 0.f;
#pragma unroll 4
  for (int jj = 0; jj < 16; jj++) {
    int j = j0 + jj;
    float pv = p1[j*IB + i];
    float rs = fmaxf(dot8s(ts, vsh[jj]), EPSF);
    float rn = fmaxf(dot8s(tn, vnh[jj]), EPSF);
    float iL = 1.f / fmaxf(rs + rn*lamv, EPSF);
    lnum += rn*pv*iL*iL;
    lden += rn*iL;
  }
  P[(jc*2+0)*IB + i] = lnum;
  P[(jc*2+1)*IB + i] = lden;
}

// ---------------- lam finalize: 512 thr = 64 i x 8 groups ----------------
__global__ __launch_bounds__(512) void k_lam_final(const float* __restrict__ P, float* __restrict__ lam,
                                                   int nchunks) {
  int tx = threadIdx.x;
  int ii = tx & 63, g = tx >> 6;
  int i = blockIdx.x * 64 + ii;
  int per = nchunks >> 3;
  float num = 0.f, den = 0.f;
  if (i < IB) {
    for (int t = 0; t < per; t++) {
      int c = g*per + t;
      num += P[(c*2+0)*IB + i];
      den += P[(c*2+1)*IB + i];
    }
  }
  __shared__ float red[2][8][64];
  red[0][g][ii] = num; red[1][g][ii] = den;
  __syncthreads();
  if (g == 0 && i < IB) {
    float n_ = 0.f, d_ = 0.f;
#pragma unroll
    for (int q=0;q<8;q++){ n_ += red[0][q][ii]; d_ += red[1][q][ii]; }
    lam[i] = fmaxf(lam[i] * sqrtf(n_/(d_+EPSF)), EPSF);
  }
}

// ---------------- G partials; 256 thr, 16 j per block ----------------
__global__ __launch_bounds__(256) void k_g_partial(const float2* __restrict__ X2,
    const float* __restrict__ Ts, const float* __restrict__ Vs,
    const float* __restrict__ Tn, const float* __restrict__ Vn,
    const float* __restrict__ lam, float* __restrict__ P) {
  __shared__ float vsh[16][8], vnh[16][8];
  int tx = threadIdx.x;
  int i = blockIdx.x * 256 + tx;
  int jc = blockIdx.y;
  int j0 = jc * 16;
  STAGE_V16(vsh, vnh, Vs, Vn, j0);
  if (i >= IB) return;
  float ts[8], tn[8];
  load8(Ts, i, ts); load8(Tn, i, tn);
  float lamv = lam[i];
  float g[8];
#pragma unroll
  for (int v=0;v<8;v++) g[v] = 0.f;
#pragma unroll 4
  for (int jj = 0; jj < 16; jj++) {
    int j = j0 + jj;
    float2 x0 = X2[j*IB + i];
    float2 x1 = X2[(JF + j)*IB + i];
    float rs = fmaxf(dot8s(ts, vsh[jj]), EPSF);
    float rn = fmaxf(dot8s(tn, vnh[jj]), EPSF);
    float ws = 1.f / fmaxf(rs + rn*lamv, EPSF);
    float wn = 1.f / rn;
    float m00 = x0.x*x0.x + x0.y*x0.y;
    float m11 = x1.x*x1.x + x1.y*x1.y;
    float m01r = x0.x*x1.x + x0.y*x1.y;
    float m01i = x0.y*x1.x - x0.x*x1.y;
    g[0] += m00*ws; g[1] += m11*ws; g[2] += m01r*ws; g[3] += m01i*ws;
    g[4] += m00*wn; g[5] += m11*wn; g[6] += m01r*wn; g[7] += m01i*wn;
  }
#pragma unroll
  for (int v=0;v<8;v++) P[(jc*8+v)*IB + i] = g[v];
}

// ---------------- per-bin 2x2 eig (LAPACK zheevd convention) ----------------
__device__ void dlaev2_dev(double a, double b, double c,
                           double& rt1, double& rt2, double& cs1, double& sn1) {
  double sm = a + c, df = a - c;
  double adf = fabs(df);
  double tb = b + b;
  double ab = fabs(tb);
  double acmx, acmn;
  if (fabs(a) > fabs(c)) { acmx = a; acmn = c; } else { acmx = c; acmn = a; }
  double rt;
  if (adf > ab)      { double t = ab/adf; rt = adf*sqrt(1.0 + t*t); }
  else if (adf < ab) { double t = adf/ab; rt = ab*sqrt(1.0 + t*t); }
  else               rt = ab*sqrt(2.0);
  int sgn1;
  if (sm < 0.0)      { rt1 = 0.5*(sm - rt); sgn1 = -1; rt2 = (acmx/rt1)*acmn - (b/rt1)*b; }
  else if (sm > 0.0) { rt1 = 0.5*(sm + rt); sgn1 =  1; rt2 = (acmx/rt1)*acmn - (b/rt1)*b; }
  else               { rt1 = 0.5*rt; rt2 = -0.5*rt; sgn1 = 1; }
  double cs; int sgn2;
  if (df >= 0.0) { cs = df + rt; sgn2 = 1; } else { cs = df - rt; sgn2 = -1; }
  double acs = fabs(cs);
  if (acs > ab) {
    double ct = -tb/cs;
    sn1 = 1.0/sqrt(1.0 + ct*ct);
    cs1 = ct*sn1;
  } else {
    if (ab == 0.0) { cs1 = 1.0; sn1 = 0.0; }
    else { double tn = -cs/tb; cs1 = 1.0/sqrt(1.0 + tn*tn); sn1 = tn*cs1; }
  }
  if (sgn1 == sgn2) { double tn = cs1; cs1 = -sn1; sn1 = tn; }
}

// ---------------- fused G finalize + eig: 512 thr = 64 i x 8 v-groups ----------------
__global__ __launch_bounds__(512) void k_geig(const float* __restrict__ P, float* __restrict__ Wm) {
  int tx = threadIdx.x;
  int ii = tx & 63, v = tx >> 6;   // v in 0..7
  int i = blockIdx.x * 64 + ii;
  double s = 0.0;
  if (i < IB) {
    for (int c = 0; c < NCH; c++) s += (double)P[(c*8+v)*IB + i];
  }
  __shared__ double gsh[8][64];
  gsh[v][ii] = s;
  __syncthreads();
  if (v != 0 || i >= IB) return;
  const double EPSD = 1e-10;
  double as  = gsh[0][ii]/4096.0 + EPSD;
  double cs_ = gsh[1][ii]/4096.0 + EPSD;
  double bsr = gsh[2][ii]/4096.0, bsi = gsh[3][ii]/4096.0;
  double dn  = gsh[4][ii]/4096.0 + EPSD;
  double fn  = gsh[5][ii]/4096.0 + EPSD;
  double enr = gsh[6][ii]/4096.0, eni = gsh[7][ii]/4096.0;
  double l11 = sqrt(as);
  double il11 = 1.0/l11;
  double l21r = bsr*il11, l21i = -bsi*il11;
  double l22sq = cs_ - (l21r*l21r + l21i*l21i);
  double l22 = sqrt(fmax(l22sq, 0.0));
  double p = il11, r = 1.0/l22;
  double qr = -l21r*p*r, qi = -l21i*p*r;
  double C00  = p*p*dn;
  double C01r = p*(dn*qr + enr*r);
  double C01i = p*(-dn*qi + eni*r);
  double C11  = (qr*qr+qi*qi)*dn + 2.0*r*(qr*enr - qi*eni) + r*r*fn;
  double br = C01r, bi = C01i;
  double e_, hqr, hqi;
  if (bi == 0.0) { e_ = br; hqr = 1.0; hqi = 0.0; }
  else {
    double ab_ = sqrt(br*br + bi*bi);
    e_ = (br >= 0.0) ? -ab_ : ab_;
    hqr = br / e_; hqi = -bi / e_;
  }
  double ut0, ub0, ut1, ub1;
  const double MEPS = 1.1102230246251565e-16;
  if (fabs(e_) <= sqrt(fabs(C00))*sqrt(fabs(C11))*MEPS) {
    if (C11 < C00) { ut0=0.0; ub0=1.0; ut1=1.0; ub1=0.0; }
    else           { ut0=1.0; ub0=0.0; ut1=0.0; ub1=1.0; }
  } else {
    double rt1, rt2, cs1, sn1;
    dlaev2_dev(C00, e_, C11, rt1, rt2, cs1, sn1);
    if (rt2 < rt1) { ut0=-sn1; ub0=cs1; ut1=cs1;  ub1=sn1; }
    else           { ut0=cs1;  ub0=sn1; ut1=-sn1; ub1=cs1; }
  }
  double chr = qr*hqr + qi*hqi;
  double chi = qr*hqi - qi*hqr;
  double v0tr = p*ut0 + chr*ub0, v0ti = chi*ub0;
  double v0br = r*hqr*ub0,       v0bi = r*hqi*ub0;
  double v1tr = p*ut1 + chr*ub1, v1ti = chi*ub1;
  double v1br = r*hqr*ub1,       v1bi = r*hqi*ub1;
  double q0 = as*(v0tr*v0tr+v0ti*v0ti) + cs_*(v0br*v0br+v0bi*v0bi)
            + 2.0*((bsr*v0br - bsi*v0bi)*v0tr + (bsr*v0bi + bsi*v0br)*v0ti);
  double q1 = dn*(v1tr*v1tr+v1ti*v1ti) + fn*(v1br*v1br+v1bi*v1bi)
            + 2.0*((enr*v1br - eni*v1bi)*v1tr + (enr*v1bi + eni*v1br)*v1ti);
  double s0 = 1.0/sqrt(fmax(q0, 1e-10));
  double s1 = 1.0/sqrt(fmax(q1, 1e-10));
  float* w = Wm + i*8;
  w[0] = (float)(v0tr*s0); w[1] = (float)(v0ti*s0);
  w[2] = (float)(v0br*s0); w[3] = (float)(v0bi*s0);
  w[4] = (float)(v1tr*s1); w[5] = (float)(v1ti*s1);
  w[6] = (float)(v1br*s1); w[7] = (float)(v1bi*s1);
}

// ---------------- fused: p1/pn + r-init + first simplified iteration + lam partials ----------------
__global__ __launch_bounds__(256) void k_rinit_simp(const float2* __restrict__ X2,
    const float* __restrict__ Wm,
    const float* __restrict__ Ts, const float* __restrict__ Vs,
    const float* __restrict__ Tn, const float* __restrict__ Vn,
    const float* __restrict__ lam,
    float* __restrict__ p1, float* __restrict__ pn, float2* __restrict__ m0,
    float* __restrict__ P) {
  __shared__ float vsh[16][8], vnh[16][8];
  int tx = threadIdx.x;
  int i = blockIdx.x * 256 + tx;
  int jc = blockIdx.y;
  int j0 = jc * 16;
  STAGE_V16(vsh, vnh, Vs, Vn, j0);
  if (i >= IB) return;
  float ts[8], tn[8];
  load8(Ts, i, ts); load8(Tn, i, tn);
  float lamv = lam[i];
  const float4* W4 = (const float4*)Wm;
  float4 wa = W4[i*2], wb = W4[i*2+1];
  float lnum = 0.f, lden = 0.f;
#pragma unroll 4
  for (int jj = 0; jj < 16; jj++) {
    int j = j0 + jj;
    float2 x0 = X2[j*IB + i];
    float2 x1 = X2[(JF + j)*IB + i];
    float y0r = wa.x*x0.x + wa.y*x0.y + wa.z*x1.x + wa.w*x1.y;
    float y0i = wa.x*x0.y - wa.y*x0.x + wa.z*x1.y - wa.w*x1.x;
    float y1r = wb.x*x0.x + wb.y*x0.y + wb.z*x1.x + wb.w*x1.y;
    float y1i = wb.x*x0.y - wb.y*x0.x + wb.z*x1.y - wb.w*x1.x;
    float pv  = y0r*y0r + y0i*y0i;
    float pnv = y1r*y1r + y1i*y1i;
    p1[j*IB + i] = pv;
    pn[j*IB + i] = pnv;
    float rs = fmaxf(dot8s(ts, vsh[jj]), EPSF);
    float rn = fmaxf(dot8s(tn, vnh[jj]), EPSF);
    // iteration-5 (first simplified) update
    float iL = 1.f / fmaxf(rs + rn*lamv, EPSF);
    float irs = 1.f / (rs + EPSF);
    float rs2 = fmaxf(rs * sqrtf((pv*iL*iL) / (iL + 1.1f*irs + EPSF)), EPSF);
    float iL2 = 1.f / fmaxf(rs2 + rn*lamv, EPSF);
    float irn = 1.f / (rn + EPSF);
    float rn2 = fmaxf(rn * sqrtf((lamv*pv*iL2*iL2 + pnv*irn*irn) / (lamv*iL2 + irn + EPSF)), EPSF);
    float iL3 = 1.f / fmaxf(rs2 + rn2*lamv, EPSF);
    m0[j*IB + i] = make_float2(rs2, rn2);
    lnum += rn2*pv*iL3*iL3;
    lden += rn2*iL3;
  }
  P[(jc*2+0)*IB + i] = lnum;
  P[(jc*2+1)*IB + i] = lden;
}

// ---------------- simplified iterations; 256 thr, 16 j per block ----------------
__global__ __launch_bounds__(256) void k_simp(float2* __restrict__ m0,
    const float* __restrict__ p1, const float* __restrict__ pn,
    const float* __restrict__ lam, float* __restrict__ P) {
  int tx = threadIdx.x;
  int i = blockIdx.x * 256 + tx;
  int jc = blockIdx.y;
  if (i >= IB) return;
  float lamv = lam[i];
  float lnum = 0.f, lden = 0.f;
  int j0 = jc * 16;
#pragma unroll 4
  for (int jj = 0; jj < 16; jj++) {
    int j = j0 + jj;
    float2 rr = m0[j*IB + i];
    float rs = rr.x, rn = rr.y;
    float pv = p1[j*IB + i], pnv = pn[j*IB + i];
    float iL = 1.f / fmaxf(rs + rn*lamv, EPSF);
    float irs = 1.f / (rs + EPSF);
    float rs2 = fmaxf(rs * sqrtf((pv*iL*iL) / (iL + 1.1f*irs + EPSF)), EPSF);
    float iL2 = 1.f / fmaxf(rs2 + rn*lamv, EPSF);
    float irn = 1.f / (rn + EPSF);
    float rn2 = fmaxf(rn * sqrtf((lamv*pv*iL2*iL2 + pnv*irn*irn) / (lamv*iL2 + irn + EPSF)), EPSF);
    float iL3 = 1.f / fmaxf(rs2 + rn2*lamv, EPSF);
    m0[j*IB + i] = make_float2(rs2, rn2);
    lnum += rn2*pv*iL3*iL3;
    lden += rn2*iL3;
  }
  P[(jc*2+0)*IB + i] = lnum;
  P[(jc*2+1)*IB + i] = lden;
}

// ---------------- final: S = r_s/Lam * Y0 ----------------
__global__ __launch_bounds__(256) void k_final(float2* __restrict__ m0, float2* __restrict__ m1,
    const float2* __restrict__ X2, const float* __restrict__ Wm, const float* __restrict__ lam) {
  int i = blockIdx.x * 256 + threadIdx.x;
  int j = blockIdx.y;
  if (i >= IB) return;
  float2 rr = m0[j*IB + i];
  float L = fmaxf(rr.x + rr.y*lam[i], EPSF);
  float gsc = rr.x / L;
  float2 x0 = X2[j*IB + i];
  float2 x1 = X2[(JF + j)*IB + i];
  float4 wa = ((const float4*)Wm)[i*2];
  float y0r = wa.x*x0.x + wa.y*x0.y + wa.z*x1.x + wa.w*x1.y;
  float y0i = wa.x*x0.y - wa.y*x0.x + wa.z*x1.y - wa.w*x1.x;
  float2 s = make_float2(gsc*y0r, gsc*y0i);
  m0[j*IB + i] = s;
  m1[j*IB + i] = s;
}

// ---------------- launch ----------------
extern "C" void kernel_launch(void* const* d_in, const int* in_sizes, int n_in,
                              void* d_out, int out_size, void* d_ws, size_t ws_size,
                              hipStream_t stream) {
  (void)in_sizes; (void)n_in; (void)out_size; (void)ws_size;
  const float* X = (const float*)d_in[0];
  const float* Ts_in = (const float*)d_in[1];
  const float* Vs_in = (const float*)d_in[2];
  const float* Tn_in = (const float*)d_in[3];
  const float* Vn_in = (const float*)d_in[4];

  float* w = (float*)d_ws;
  float* Pt  = w;                      // tail lam partials: NCH*2*IB floats (reserve 1,049,600)
  float* Ts  = w + 1049600 + 16448;
  float* Vs  = Ts + 8200;
  float* Tn  = Vs + 32768;
  float* Vn  = Tn + 8200;
  float* lam = Vn + 32768;
  float* Wm  = lam + 1028;

  float* out = (float*)d_out;
  float2* m0 = (float2*)d_out;
  float2* m1 = m0 + (size_t)JF*IB;
  float* p1 = out + 2*(size_t)JF*IB;
  float* pn = p1 + (size_t)JF*IB;
  // main-loop partials live in the (dead until tail) m0 slice of d_out:
  //   T partials need NCH*16*IB = 16.8 MB; m0 slice is 33.6 MB.
  float* Pbig = out;
  const float2* X2 = (const float2*)X;

  k_init<<<dim3(128), 256, 0, stream>>>(Ts_in, Vs_in, Tn_in, Vn_in, Ts, Vs, Tn, Vn, lam, Wm);

  for (int it = 0; it < 5; it++) {
    k_p1pn_ts<<<dim3(5, NCH), 256, 0, stream>>>(X2, Wm, Ts, Vs, Tn, Vn, lam, p1, pn, Pbig);
    k_t_final<<<dim3(17, 8), 512, 0, stream>>>(Pbig, Ts);
    k_vs<<<dim3(JF), 256, 0, stream>>>(p1, Ts, Vs, Tn, Vn, lam);
    k_tn_partial<<<dim3(5, NCH), 256, 0, stream>>>(p1, pn, Ts, Vs, Tn, Vn, lam, Pbig);
    k_t_final<<<dim3(17, 8), 512, 0, stream>>>(Pbig, Tn);
    k_vn<<<dim3(JF), 256, 0, stream>>>(p1, pn, Ts, Vs, Tn, Vn, lam);
    k_lam_partial<<<dim3(5, NCH), 256, 0, stream>>>(p1, Ts, Vs, Tn, Vn, lam, Pbig);
    k_lam_final<<<dim3(17), 512, 0, stream>>>(Pbig, lam, NCH);
    k_g_partial<<<dim3(5, NCH), 256, 0, stream>>>(X2, Ts, Vs, Tn, Vn, lam, Pbig);
    k_geig<<<dim3(17), 512, 0, stream>>>(Pbig, Wm);
  }

  // tail: fused rinit + first simplified iteration
  k_rinit_simp<<<dim3(5, NCH), 256, 0, stream>>>(X2, Wm, Ts, Vs, Tn, Vn, lam, p1, pn, m0, Pt);
  k_lam_final<<<dim3(17), 512, 0, stream>>>(Pt, lam, NCH);

  for (int it = 0; it < 2; it++) {
    k_simp<<<dim3(5, NCH), 256, 0, stream>>>(m0, p1, pn, lam, Pt);
    k_lam_final<<<dim3(17), 512, 0, stream>>>(Pt, lam, NCH);
  }

  k_final<<<dim3(5, JF), 256, 0, stream>>>(m0, m1, X2, Wm, lam);
}

// Round 11
// 871.714 us; speedup vs baseline: 5.1775x; 1.0474x over previous
//
#include <hip/hip_runtime.h>
#include <math.h>

#define IB 1025
#define JF 4096
#define EPSF 1e-10f

// ---------------- helpers ----------------
__device__ __forceinline__ void load8(const float* __restrict__ base, int i, float v[8]) {
  const float4* b4 = (const float4*)(base + i * 8);
  float4 a = b4[0], b = b4[1];
  v[0]=a.x; v[1]=a.y; v[2]=a.z; v[3]=a.w; v[4]=b.x; v[5]=b.y; v[6]=b.z; v[7]=b.w;
}
__device__ __forceinline__ float dot8(const float a[8], const float b[8]) {
  float s = a[0]*b[0];
#pragma unroll
  for (int k=1;k<8;k++) s += a[k]*b[k];
  return s;
}
__device__ __forceinline__ float dot8s(const float a[8], const float* __restrict__ b) {
  float s = a[0]*b[0];
#pragma unroll
  for (int k=1;k<8;k++) s += a[k]*b[k];
  return s;
}

// ---- stage V chunk (16 j x 8 k x {s,n}) into LDS: one load per thread ----
#define STAGE_V16(vsh, vnh, Vs, Vn, j0) do {                                \
    int t_ = threadIdx.x;                                                   \
    if (t_ < 128) { int jj_ = t_ >> 3, k_ = t_ & 7;                         \
      vsh[jj_][k_] = Vs[k_*JF + (j0) + jj_]; }                              \
    else { int u_ = t_ - 128; int jj_ = u_ >> 3, k_ = u_ & 7;               \
      vnh[jj_][k_] = Vn[k_*JF + (j0) + jj_]; }                              \
    __syncthreads();                                                        \
  } while (0)

// ---------------- init ----------------
__global__ __launch_bounds__(256) void k_init(
    const float* __restrict__ Ts_in, const float* __restrict__ Vs_in,
    const float* __restrict__ Tn_in, const float* __restrict__ Vn_in,
    float* __restrict__ Ts, float* __restrict__ Vs,
    float* __restrict__ Tn, float* __restrict__ Vn,
    float* __restrict__ lam, float* __restrict__ Wm) {
  int idx = blockIdx.x * 256 + threadIdx.x;
  if (idx < 8 * JF) { Vs[idx] = Vs_in[idx]; Vn[idx] = Vn_in[idx]; }
  if (idx < IB * 8) { Ts[idx] = Ts_in[idx]; Tn[idx] = Tn_in[idx]; }
  if (idx < IB) {
    lam[idx] = 1.0f;
    float* w = Wm + idx * 8;
    w[0]=1.f; w[1]=0.f; w[2]=0.f; w[3]=0.f; w[4]=0.f; w[5]=0.f; w[6]=1.f; w[7]=0.f;
  }
}

// ---------------- fused p1/pn + T_s partials; 256 thr, 16 j per block ----------------
__global__ __launch_bounds__(256) void k_p1pn_ts(const float2* __restrict__ X2,
    const float* __restrict__ Wm,
    const float* __restrict__ Ts, const float* __restrict__ Vs,
    const float* __restrict__ Tn, const float* __restrict__ Vn,
    const float* __restrict__ lam,
    float* __restrict__ p1, float* __restrict__ pn, float* __restrict__ P) {
  __shared__ float vsh[16][8], vnh[16][8];
  int tx = threadIdx.x;
  int i = blockIdx.x * 256 + tx;
  int jc = blockIdx.y;
  int j0 = jc * 16;
  STAGE_V16(vsh, vnh, Vs, Vn, j0);
  if (i >= IB) return;
  float ts[8], tn[8];
  load8(Ts, i, ts); load8(Tn, i, tn);
  float lamv = lam[i];
  const float4* W4 = (const float4*)Wm;
  float4 wa = W4[i*2], wb = W4[i*2+1];
  float num[8] = {0,0,0,0,0,0,0,0}, den[8] = {0,0,0,0,0,0,0,0};
#pragma unroll 4
  for (int jj = 0; jj < 16; jj++) {
    int j = j0 + jj;
    float2 x0 = X2[j*IB + i];
    float2 x1 = X2[(JF + j)*IB + i];
    float y0r = wa.x*x0.x + wa.y*x0.y + wa.z*x1.x + wa.w*x1.y;
    float y0i = wa.x*x0.y - wa.y*x0.x + wa.z*x1.y - wa.w*x1.x;
    float y1r = wb.x*x0.x + wb.y*x0.y + wb.z*x1.x + wb.w*x1.y;
    float y1i = wb.x*x0.y - wb.y*x0.x + wb.z*x1.y - wb.w*x1.x;
    float pv  = y0r*y0r + y0i*y0i;
    float pnv = y1r*y1r + y1i*y1i;
    p1[j*IB + i] = pv;
    pn[j*IB + i] = pnv;
    float rs = fmaxf(dot8s(ts, vsh[jj]), EPSF);
    float rn = fmaxf(dot8s(tn, vnh[jj]), EPSF);
    float iL = 1.f / fmaxf(rs + rn*lamv, EPSF);
    float a2 = pv*iL*iL;
#pragma unroll
    for (int k=0;k<8;k++){ num[k] += a2*vsh[jj][k]; den[k] += iL*vsh[jj][k]; }
  }
#pragma unroll
  for (int k=0;k<8;k++){
    P[(jc*16+k)*IB + i] = num[k];
    P[(jc*16+8+k)*IB + i] = den[k];
  }
}

// ---------------- T finalize: 512 thr = 64 i x 8 groups, 256 chunks ----------------
__global__ __launch_bounds__(512) void k_t_final(const float* __restrict__ P, float* __restrict__ T) {
  int tx = threadIdx.x;
  int ii = tx & 63, g = tx >> 6;
  int i = blockIdx.x * 64 + ii;
  int k = blockIdx.y;
  float num = 0.f, den = 0.f;
  if (i < IB) {
    for (int t = 0; t < 32; t++) {
      int c = g*32 + t;
      num += P[(c*16+k)*IB + i];
      den += P[(c*16+8+k)*IB + i];
    }
  }
  __shared__ float red[2][8][64];
  red[0][g][ii] = num; red[1][g][ii] = den;
  __syncthreads();
  if (g == 0 && i < IB) {
    float n_ = 0.f, d_ = 0.f;
#pragma unroll
    for (int q=0;q<8;q++){ n_ += red[0][q][ii]; d_ += red[1][q][ii]; }
    float t = T[i*8+k];
    T[i*8+k] = fmaxf(t * sqrtf(n_/(d_+EPSF)), EPSF);
  }
}

// ---------------- V_s update ----------------
__global__ __launch_bounds__(256) void k_vs(const float* __restrict__ p1,
    const float* __restrict__ Ts, float* __restrict__ Vs,
    const float* __restrict__ Tn, const float* __restrict__ Vn,
    const float* __restrict__ lam) {
  int j = blockIdx.x;
  int tx = threadIdx.x;
  float vs[8], vn[8];
#pragma unroll
  for (int k=0;k<8;k++){ vs[k]=Vs[k*JF+j]; vn[k]=Vn[k*JF+j]; }
  float acc[16];
#pragma unroll
  for (int v=0;v<16;v++) acc[v] = 0.f;
  for (int s = 0; s < 5; s++) {
    int i = s*256 + tx;
    if (i < IB) {
      float ts[8], tn[8];
      load8(Ts, i, ts); load8(Tn, i, tn);
      float lamv = lam[i];
      float pv = p1[j*IB + i];
      float rs = fmaxf(dot8(ts, vs), EPSF);
      float rn = fmaxf(dot8(tn, vn), EPSF);
      float iL = 1.f / fmaxf(rs + rn*lamv, EPSF);
      float a2 = pv*iL*iL;
#pragma unroll
      for (int k=0;k<8;k++){ acc[k] += ts[k]*a2; acc[8+k] += ts[k]*iL; }
    }
  }
  __shared__ float red[4][16];
  int wid = tx >> 6, lane = tx & 63;
#pragma unroll
  for (int v=0;v<16;v++){
    float x = acc[v];
    x += __shfl_down(x, 32, 64); x += __shfl_down(x, 16, 64);
    x += __shfl_down(x, 8, 64);  x += __shfl_down(x, 4, 64);
    x += __shfl_down(x, 2, 64);  x += __shfl_down(x, 1, 64);
    if (lane == 0) red[wid][v] = x;
  }
  __syncthreads();
  if (tx == 0) {
#pragma unroll
    for (int k=0;k<8;k++){
      float n_ = red[0][k]+red[1][k]+red[2][k]+red[3][k];
      float d_ = red[0][8+k]+red[1][8+k]+red[2][8+k]+red[3][8+k];
      Vs[k*JF+j] = fmaxf(vs[k] * sqrtf(n_/(d_+EPSF)), EPSF);
    }
  }
}

// ---------------- T_n partials; 256 thr, 16 j per block ----------------
__global__ __launch_bounds__(256) void k_tn_partial(const float* __restrict__ p1,
    const float* __restrict__ pn,
    const float* __restrict__ Ts, const float* __restrict__ Vs,
    const float* __restrict__ Tn, const float* __restrict__ Vn,
    const float* __restrict__ lam, float* __restrict__ P) {
  __shared__ float vsh[16][8], vnh[16][8];
  int tx = threadIdx.x;
  int i = blockIdx.x * 256 + tx;
  int jc = blockIdx.y;
  int j0 = jc * 16;
  STAGE_V16(vsh, vnh, Vs, Vn, j0);
  if (i >= IB) return;
  float ts[8], tn[8];
  load8(Ts, i, ts); load8(Tn, i, tn);
  float lamv = lam[i];
  float num[8] = {0,0,0,0,0,0,0,0}, den[8] = {0,0,0,0,0,0,0,0};
#pragma unroll 4
  for (int jj = 0; jj < 16; jj++) {
    int j = j0 + jj;
    float pv = p1[j*IB + i];
    float pnv = pn[j*IB + i];
    float rs = fmaxf(dot8s(ts, vsh[jj]), EPSF);
    float rn = fmaxf(dot8s(tn, vnh[jj]), EPSF);
    float iL = 1.f / fmaxf(rs + rn*lamv, EPSF);
    float irn = 1.f / rn;
    float a2 = lamv*pv*iL*iL + pnv*irn*irn;
    float b2 = lamv*iL + irn;
#pragma unroll
    for (int k=0;k<8;k++){ num[k] += a2*vnh[jj][k]; den[k] += b2*vnh[jj][k]; }
  }
#pragma unroll
  for (int k=0;k<8;k++){
    P[(jc*16+k)*IB + i] = num[k];
    P[(jc*16+8+k)*IB + i] = den[k];
  }
}

// ---------------- V_n update ----------------
__global__ __launch_bounds__(256) void k_vn(const float* __restrict__ p1,
    const float* __restrict__ pn,
    const float* __restrict__ Ts, const float* __restrict__ Vs,
    const float* __restrict__ Tn, float* __restrict__ Vn,
    const float* __restrict__ lam) {
  int j = blockIdx.x;
  int tx = threadIdx.x;
  float vs[8], vn[8];
#pragma unroll
  for (int k=0;k<8;k++){ vs[k]=Vs[k*JF+j]; vn[k]=Vn[k*JF+j]; }
  float acc[16];
#pragma unroll
  for (int v=0;v<16;v++) acc[v] = 0.f;
  for (int s = 0; s < 5; s++) {
    int i = s*256 + tx;
    if (i < IB) {
      float ts[8], tn[8];
      load8(Ts, i, ts); load8(Tn, i, tn);
      float lamv = lam[i];
      float pv = p1[j*IB + i];
      float pnv = pn[j*IB + i];
      float rs = fmaxf(dot8(ts, vs), EPSF);
      float rn = fmaxf(dot8(tn, vn), EPSF);
      float iL = 1.f / fmaxf(rs + rn*lamv, EPSF);
      float irn = 1.f / rn;
      float a2 = lamv*pv*iL*iL + pnv*irn*irn;
      float b2 = lamv*iL + irn;
#pragma unroll
      for (int k=0;k<8;k++){ acc[k] += tn[k]*a2; acc[8+k] += tn[k]*b2; }
    }
  }
  __shared__ float red[4][16];
  int wid = tx >> 6, lane = tx & 63;
#pragma unroll
  for (int v=0;v<16;v++){
    float x = acc[v];
    x += __shfl_down(x, 32, 64); x += __shfl_down(x, 16, 64);
    x += __shfl_down(x, 8, 64);  x += __shfl_down(x, 4, 64);
    x += __shfl_down(x, 2, 64);  x += __shfl_down(x, 1, 64);
    if (lane == 0) red[wid][v] = x;
  }
  __syncthreads();
  if (tx == 0) {
#pragma unroll
    for (int k=0;k<8;k++){
      float n_ = red[0][k]+red[1][k]+red[2][k]+red[3][k];
      float d_ = red[0][8+k]+red[1][8+k]+red[2][8+k]+red[3][8+k];
      Vn[k*JF+j] = fmaxf(vn[k] * sqrtf(n_/(d_+EPSF)), EPSF);
    }
  }
}

// ---------------- lam partials; 256 thr, 16 j per block ----------------
__global__ __launch_bounds__(256) void k_lam_partial(const float* __restrict__ p1,
    const float* __restrict__ Ts, const float* __restrict__ Vs,
    const float* __restrict__ Tn, const float* __restrict__ Vn,
    const float* __restrict__ lam, float* __restrict__ P) {
  __shared__ float vsh[16][8], vnh[16][8];
  int tx = threadIdx.x;
  int i = blockIdx.x * 256 + tx;
  int jc = blockIdx.y;
  int j0 = jc * 16;
  STAGE_V16(vsh, vnh, Vs, Vn, j0);
  if (i >= IB) return;
  float ts[8], tn[8];
  load8(Ts, i, ts); load8(Tn, i, tn);
  float lamv = lam[i];
  float lnum = 0.f, lden = 0.f;
#pragma unroll 4
  for (int jj = 0; jj < 16; jj++) {
    int j = j0 + jj;
    float pv = p1[j*IB + i];
    float rs = fmaxf(dot8s(ts, vsh[jj]), EPSF);
    float rn = fmaxf(dot8s(tn, vnh[jj]), EPSF);
    float iL = 1.f / fmaxf(rs + rn*lamv, EPSF);
    lnum += rn*pv*iL*iL;
    lden += rn*iL;
  }
  P[(jc*2+0)*IB + i] = lnum;
  P[(jc*2+1)*IB + i] = lden;
}

// ---------------- lam finalize: 512 thr = 64 i x 8 groups ----------------
__global__ __launch_bounds__(512) void k_lam_final(const float* __restrict__ P, float* __restrict__ lam,
                                                   int nchunks) {
  int tx = threadIdx.x;
  int ii = tx & 63, g = tx >> 6;
  int i = blockIdx.x * 64 + ii;
  int per = nchunks >> 3;
  float num = 0.f, den = 0.f;
  if (i < IB) {
    for (int t = 0; t < per; t++) {
      int c = g*per + t;
      num += P[(c*2+0)*IB + i];
      den += P[(c*2+1)*IB + i];
    }
  }
  __shared__ float red[2][8][64];
  red[0][g][ii] = num; red[1][g][ii] = den;
  __syncthreads();
  if (g == 0 && i < IB) {
    float n_ = 0.f, d_ = 0.f;
#pragma unroll
    for (int q=0;q<8;q++){ n_ += red[0][q][ii]; d_ += red[1][q][ii]; }
    lam[i] = fmaxf(lam[i] * sqrtf(n_/(d_+EPSF)), EPSF);
  }
}

// ---------------- G partials; 256 thr, 16 j per block ----------------
__global__ __launch_bounds__(256) void k_g_partial(const float2* __restrict__ X2,
    const float* __restrict__ Ts, const float* __restrict__ Vs,
    const float* __restrict__ Tn, const float* __restrict__ Vn,
    const float* __restrict__ lam, float* __restrict__ P) {
  __shared__ float vsh[16][8], vnh[16][8];
  int tx = threadIdx.x;
  int i = blockIdx.x * 256 + tx;
  int jc = blockIdx.y;
  int j0 = jc * 16;
  STAGE_V16(vsh, vnh, Vs, Vn, j0);
  if (i >= IB) return;
  float ts[8], tn[8];
  load8(Ts, i, ts); load8(Tn, i, tn);
  float lamv = lam[i];
  float g[8];
#pragma unroll
  for (int v=0;v<8;v++) g[v] = 0.f;
#pragma unroll 4
  for (int jj = 0; jj < 16; jj++) {
    int j = j0 + jj;
    float2 x0 = X2[j*IB + i];
    float2 x1 = X2[(JF + j)*IB + i];
    float rs = fmaxf(dot8s(ts, vsh[jj]), EPSF);
    float rn = fmaxf(dot8s(tn, vnh[jj]), EPSF);
    float ws = 1.f / fmaxf(rs + rn*lamv, EPSF);
    float wn = 1.f / rn;
    float m00 = x0.x*x0.x + x0.y*x0.y;
    float m11 = x1.x*x1.x + x1.y*x1.y;
    float m01r = x0.x*x1.x + x0.y*x1.y;
    float m01i = x0.y*x1.x - x0.x*x1.y;
    g[0] += m00*ws; g[1] += m11*ws; g[2] += m01r*ws; g[3] += m01i*ws;
    g[4] += m00*wn; g[5] += m11*wn; g[6] += m01r*wn; g[7] += m01i*wn;
  }
#pragma unroll
  for (int v=0;v<8;v++) P[(jc*8+v)*IB + i] = g[v];
}

// ---------------- G finalize: 512 thr = 64 i x 8 groups, 256 chunks ----------------
__global__ __launch_bounds__(512) void k_g_final(const float* __restrict__ P, double* __restrict__ Gd) {
  int tx = threadIdx.x;
  int ii = tx & 63, g = tx >> 6;
  int i = blockIdx.x * 64 + ii;
  int v = blockIdx.y;
  double s = 0.0;
  if (i < IB) {
    for (int t = 0; t < 32; t++) {
      int c = g*32 + t;
      s += (double)P[(c*8+v)*IB + i];
    }
  }
  __shared__ double red[8][64];
  red[g][ii] = s;
  __syncthreads();
  if (g == 0 && i < IB) {
    double acc = 0.0;
#pragma unroll
    for (int q=0;q<8;q++) acc += red[q][ii];
    Gd[v*1028 + i] = acc;
  }
}

// ---------------- per-bin 2x2 eig (LAPACK zheevd convention) ----------------
__device__ void dlaev2_dev(double a, double b, double c,
                           double& rt1, double& rt2, double& cs1, double& sn1) {
  double sm = a + c, df = a - c;
  double adf = fabs(df);
  double tb = b + b;
  double ab = fabs(tb);
  double acmx, acmn;
  if (fabs(a) > fabs(c)) { acmx = a; acmn = c; } else { acmx = c; acmn = a; }
  double rt;
  if (adf > ab)      { double t = ab/adf; rt = adf*sqrt(1.0 + t*t); }
  else if (adf < ab) { double t = adf/ab; rt = ab*sqrt(1.0 + t*t); }
  else               rt = ab*sqrt(2.0);
  int sgn1;
  if (sm < 0.0)      { rt1 = 0.5*(sm - rt); sgn1 = -1; rt2 = (acmx/rt1)*acmn - (b/rt1)*b; }
  else if (sm > 0.0) { rt1 = 0.5*(sm + rt); sgn1 =  1; rt2 = (acmx/rt1)*acmn - (b/rt1)*b; }
  else               { rt1 = 0.5*rt; rt2 = -0.5*rt; sgn1 = 1; }
  double cs; int sgn2;
  if (df >= 0.0) { cs = df + rt; sgn2 = 1; } else { cs = df - rt; sgn2 = -1; }
  double acs = fabs(cs);
  if (acs > ab) {
    double ct = -tb/cs;
    sn1 = 1.0/sqrt(1.0 + ct*ct);
    cs1 = ct*sn1;
  } else {
    if (ab == 0.0) { cs1 = 1.0; sn1 = 0.0; }
    else { double tn = -cs/tb; cs1 = 1.0/sqrt(1.0 + tn*tn); sn1 = tn*cs1; }
  }
  if (sgn1 == sgn2) { double tn = cs1; cs1 = -sn1; sn1 = tn; }
}

__global__ __launch_bounds__(64) void k_eig(const double* __restrict__ Gd, float* __restrict__ Wm) {
  int i = blockIdx.x * 64 + threadIdx.x;
  if (i >= IB) return;
  double g[8];
#pragma unroll
  for (int v=0;v<8;v++) g[v] = Gd[v*1028 + i];
  const double EPSD = 1e-10;
  double as  = g[0]/4096.0 + EPSD;
  double cs_ = g[1]/4096.0 + EPSD;
  double bsr = g[2]/4096.0, bsi = g[3]/4096.0;
  double dn  = g[4]/4096.0 + EPSD;
  double fn  = g[5]/4096.0 + EPSD;
  double enr = g[6]/4096.0, eni = g[7]/4096.0;
  double l11 = sqrt(as);
  double il11 = 1.0/l11;
  double l21r = bsr*il11, l21i = -bsi*il11;
  double l22sq = cs_ - (l21r*l21r + l21i*l21i);
  double l22 = sqrt(fmax(l22sq, 0.0));
  double p = il11, r = 1.0/l22;
  double qr = -l21r*p*r, qi = -l21i*p*r;
  double C00  = p*p*dn;
  double C01r = p*(dn*qr + enr*r);
  double C01i = p*(-dn*qi + eni*r);
  double C11  = (qr*qr+qi*qi)*dn + 2.0*r*(qr*enr - qi*eni) + r*r*fn;
  double br = C01r, bi = C01i;
  double e_, hqr, hqi;
  if (bi == 0.0) { e_ = br; hqr = 1.0; hqi = 0.0; }
  else {
    double ab_ = sqrt(br*br + bi*bi);
    e_ = (br >= 0.0) ? -ab_ : ab_;
    hqr = br / e_; hqi = -bi / e_;
  }
  double ut0, ub0, ut1, ub1;
  const double MEPS = 1.1102230246251565e-16;
  if (fabs(e_) <= sqrt(fabs(C00))*sqrt(fabs(C11))*MEPS) {
    if (C11 < C00) { ut0=0.0; ub0=1.0; ut1=1.0; ub1=0.0; }
    else           { ut0=1.0; ub0=0.0; ut1=0.0; ub1=1.0; }
  } else {
    double rt1, rt2, cs1, sn1;
    dlaev2_dev(C00, e_, C11, rt1, rt2, cs1, sn1);
    if (rt2 < rt1) { ut0=-sn1; ub0=cs1; ut1=cs1;  ub1=sn1; }
    else           { ut0=cs1;  ub0=sn1; ut1=-sn1; ub1=cs1; }
  }
  double chr = qr*hqr + qi*hqi;
  double chi = qr*hqi - qi*hqr;
  double v0tr = p*ut0 + chr*ub0, v0ti = chi*ub0;
  double v0br = r*hqr*ub0,       v0bi = r*hqi*ub0;
  double v1tr = p*ut1 + chr*ub1, v1ti = chi*ub1;
  double v1br = r*hqr*ub1,       v1bi = r*hqi*ub1;
  double q0 = as*(v0tr*v0tr+v0ti*v0ti) + cs_*(v0br*v0br+v0bi*v0bi)
            + 2.0*((bsr*v0br - bsi*v0bi)*v0tr + (bsr*v0bi + bsi*v0br)*v0ti);
  double q1 = dn*(v1tr*v1tr+v1ti*v1ti) + fn*(v1br*v1br+v1bi*v1bi)
            + 2.0*((enr*v1br - eni*v1bi)*v1tr + (enr*v1bi + eni*v1br)*v1ti);
  double s0 = 1.0/sqrt(fmax(q0, 1e-10));
  double s1 = 1.0/sqrt(fmax(q1, 1e-10));
  float* w = Wm + i*8;
  w[0] = (float)(v0tr*s0); w[1] = (float)(v0ti*s0);
  w[2] = (float)(v0br*s0); w[3] = (float)(v0bi*s0);
  w[4] = (float)(v1tr*s1); w[5] = (float)(v1ti*s1);
  w[6] = (float)(v1br*s1); w[7] = (float)(v1bi*s1);
}

// ---------------- p1/pn + (r_s,r_n) into m0 ----------------
__global__ __launch_bounds__(256) void k_p1pn_rinit(const float2* __restrict__ X2,
    const float* __restrict__ Wm,
    const float* __restrict__ Ts, const float* __restrict__ Vs,
    const float* __restrict__ Tn, const float* __restrict__ Vn,
    float* __restrict__ p1, float* __restrict__ pn, float2* __restrict__ m0) {
  int i = blockIdx.x * 256 + threadIdx.x;
  int j = blockIdx.y;
  if (i >= IB) return;
  float2 x0 = X2[j*IB + i];
  float2 x1 = X2[(JF + j)*IB + i];
  const float4* W4 = (const float4*)Wm;
  float4 wa = W4[i*2], wb = W4[i*2+1];
  float y0r = wa.x*x0.x + wa.y*x0.y + wa.z*x1.x + wa.w*x1.y;
  float y0i = wa.x*x0.y - wa.y*x0.x + wa.z*x1.y - wa.w*x1.x;
  float y1r = wb.x*x0.x + wb.y*x0.y + wb.z*x1.x + wb.w*x1.y;
  float y1i = wb.x*x0.y - wb.y*x0.x + wb.z*x1.y - wb.w*x1.x;
  p1[j*IB + i] = y0r*y0r + y0i*y0i;
  pn[j*IB + i] = y1r*y1r + y1i*y1i;
  float ts[8], tn[8];
  load8(Ts, i, ts); load8(Tn, i, tn);
  float rs = 0.f, rn = 0.f;
#pragma unroll
  for (int k=0;k<8;k++){ rs += ts[k]*Vs[k*JF+j]; rn += tn[k]*Vn[k*JF+j]; }
  m0[j*IB + i] = make_float2(fmaxf(rs, EPSF), fmaxf(rn, EPSF));
}

// ---------------- simplified iterations; 256 thr, 16 j per block ----------------
__global__ __launch_bounds__(256) void k_simp(float2* __restrict__ m0,
    const float* __restrict__ p1, const float* __restrict__ pn,
    const float* __restrict__ lam, float* __restrict__ P) {
  int tx = threadIdx.x;
  int i = blockIdx.x * 256 + tx;
  int jc = blockIdx.y;
  if (i >= IB) return;
  float lamv = lam[i];
  float lnum = 0.f, lden = 0.f;
  int j0 = jc * 16;
#pragma unroll 4
  for (int jj = 0; jj < 16; jj++) {
    int j = j0 + jj;
    float2 rr = m0[j*IB + i];
    float rs = rr.x, rn = rr.y;
    float pv = p1[j*IB + i], pnv = pn[j*IB + i];
    float iL = 1.f / fmaxf(rs + rn*lamv, EPSF);
    float irs = 1.f / (rs + EPSF);
    float rs2 = fmaxf(rs * sqrtf((pv*iL*iL) / (iL + 1.1f*irs + EPSF)), EPSF);
    float iL2 = 1.f / fmaxf(rs2 + rn*lamv, EPSF);
    float irn = 1.f / (rn + EPSF);
    float rn2 = fmaxf(rn * sqrtf((lamv*pv*iL2*iL2 + pnv*irn*irn) / (lamv*iL2 + irn + EPSF)), EPSF);
    float iL3 = 1.f / fmaxf(rs2 + rn2*lamv, EPSF);
    m0[j*IB + i] = make_float2(rs2, rn2);
    lnum += rn2*pv*iL3*iL3;
    lden += rn2*iL3;
  }
  P[(jc*2+0)*IB + i] = lnum;
  P[(jc*2+1)*IB + i] = lden;
}

// ---------------- final: S = r_s/Lam * Y0 ----------------
__global__ __launch_bounds__(256) void k_final(float2* __restrict__ m0, float2* __restrict__ m1,
    const float2* __restrict__ X2, const float* __restrict__ Wm, const float* __restrict__ lam) {
  int i = blockIdx.x * 256 + threadIdx.x;
  int j = blockIdx.y;
  if (i >= IB) return;
  float2 rr = m0[j*IB + i];
  float L = fmaxf(rr.x + rr.y*lam[i], EPSF);
  float gsc = rr.x / L;
  float2 x0 = X2[j*IB + i];
  float2 x1 = X2[(JF + j)*IB + i];
  float4 wa = ((const float4*)Wm)[i*2];
  float y0r = wa.x*x0.x + wa.y*x0.y + wa.z*x1.x + wa.w*x1.y;
  float y0i = wa.x*x0.y - wa.y*x0.x + wa.z*x1.y - wa.w*x1.x;
  float2 s = make_float2(gsc*y0r, gsc*y0i);
  m0[j*IB + i] = s;
  m1[j*IB + i] = s;
}

// ---------------- launch ----------------
extern "C" void kernel_launch(void* const* d_in, const int* in_sizes, int n_in,
                              void* d_out, int out_size, void* d_ws, size_t ws_size,
                              hipStream_t stream) {
  (void)in_sizes; (void)n_in; (void)out_size; (void)ws_size;
  const float* X = (const float*)d_in[0];
  const float* Ts_in = (const float*)d_in[1];
  const float* Vs_in = (const float*)d_in[2];
  const float* Tn_in = (const float*)d_in[3];
  const float* Vn_in = (const float*)d_in[4];

  float* w = (float*)d_ws;
  float* Pt  = w;                      // tail lam partials: 256*2*IB floats (reserve 1,049,600)
  double* Gd = (double*)(w + 1049600);
  float* Ts  = w + 1049600 + 16448;
  float* Vs  = Ts + 8200;
  float* Tn  = Vs + 32768;
  float* Vn  = Tn + 8200;
  float* lam = Vn + 32768;
  float* Wm  = lam + 1028;

  float* out = (float*)d_out;
  float2* m0 = (float2*)d_out;
  float2* m1 = m0 + (size_t)JF*IB;
  float* p1 = out + 2*(size_t)JF*IB;
  float* pn = p1 + (size_t)JF*IB;
  // main-loop partials live in the (dead until tail) m0 slice of d_out:
  //   T partials need 256*16*IB = 16.8 MB; m0 slice is 33.6 MB.
  float* Pbig = out;
  const float2* X2 = (const float2*)X;

  k_init<<<dim3(128), 256, 0, stream>>>(Ts_in, Vs_in, Tn_in, Vn_in, Ts, Vs, Tn, Vn, lam, Wm);

  for (int it = 0; it < 5; it++) {
    k_p1pn_ts<<<dim3(5, 256), 256, 0, stream>>>(X2, Wm, Ts, Vs, Tn, Vn, lam, p1, pn, Pbig);
    k_t_final<<<dim3(17, 8), 512, 0, stream>>>(Pbig, Ts);
    k_vs<<<dim3(JF), 256, 0, stream>>>(p1, Ts, Vs, Tn, Vn, lam);
    k_tn_partial<<<dim3(5, 256), 256, 0, stream>>>(p1, pn, Ts, Vs, Tn, Vn, lam, Pbig);
    k_t_final<<<dim3(17, 8), 512, 0, stream>>>(Pbig, Tn);
    k_vn<<<dim3(JF), 256, 0, stream>>>(p1, pn, Ts, Vs, Tn, Vn, lam);
    k_lam_partial<<<dim3(5, 256), 256, 0, stream>>>(p1, Ts, Vs, Tn, Vn, lam, Pbig);
    k_lam_final<<<dim3(17), 512, 0, stream>>>(Pbig, lam, 256);
    k_g_partial<<<dim3(5, 256), 256, 0, stream>>>(X2, Ts, Vs, Tn, Vn, lam, Pbig);
    k_g_final<<<dim3(17, 8), 512, 0, stream>>>(Pbig, Gd);
    k_eig<<<dim3(17), 64, 0, stream>>>(Gd, Wm);
  }

  k_p1pn_rinit<<<dim3(5, JF), 256, 0, stream>>>(X2, Wm, Ts, Vs, Tn, Vn, p1, pn, m0);

  for (int it = 0; it < 3; it++) {
    k_simp<<<dim3(5, 256), 256, 0, stream>>>(m0, p1, pn, lam, Pt);
    k_lam_final<<<dim3(17), 512, 0, stream>>>(Pt, lam, 256);
  }

  k_final<<<dim3(5, JF), 256, 0, stream>>>(m0, m1, X2, Wm, lam);
}